// Round 5
// baseline (127.035 us; speedup 1.0000x reference)
//
#include <hip/hip_runtime.h>

// Problem constants (reference: N=16384, K=32, D=256)
#define N_ 16384
#define K_ 32
#define D_ 256
#define NEG_SLOPE 0.01f

// ---------------------------------------------------------------------------
// Prologue (parallel): ws[0..255] = v = a_w @ W, ws[256] = 2*dot(b,a_w)+a_b.
// ws zeroed by hipMemsetAsync; 32 blocks accumulate via atomicAdd.
// ---------------------------------------------------------------------------
__global__ __launch_bounds__(256) void prep_kernel(
    const float* __restrict__ W, const float* __restrict__ b,
    const float* __restrict__ a_w, const float* __restrict__ a_b,
    float* __restrict__ ws) {
  const int t = threadIdx.x;  // column e
  const int i = blockIdx.x;   // 0..31
  float acc = 0.f;
#pragma unroll
  for (int j = 0; j < 8; ++j) {
    const int d = i * 8 + j;
    acc += a_w[d] * W[d * D_ + t];
  }
  atomicAdd(&ws[t], acc);

  if (i == 0) {
    float s = b[t] * a_w[t];
#pragma unroll
    for (int off = 1; off < 64; off <<= 1) s += __shfl_xor(s, off);
    __shared__ float sp[4];
    if ((t & 63) == 0) sp[t >> 6] = s;
    __syncthreads();
    if (t == 0)
      atomicAdd(&ws[D_], 2.f * (sp[0] + sp[1] + sp[2] + sp[3]) + a_b[0]);
  }
}

// ---------------------------------------------------------------------------
// Main: ONE WAVE PER n — no LDS, no __syncthreads, no vmcnt(0) barrier
// drains. Lane l owns columns 4l..4l+3 of all K=32 rows (m[32] = 128 VGPR).
//   pass 1: per-row dots reduced by a value-halving butterfly
//           (after it, lane pair {2j,2j+1} holds the full dot of row j)
//   softmax: fully in-wave (fmax/sum butterflies; every j appears twice,
//            so the lane-sum is 2*sum_j -> coef = 2*ex/sum)
//   pass 2: coef broadcast via readlane (SALU), FMA on registers, float4 out.
// Waves retire independently -> CU always has 8 streams issuing VMEM.
// ---------------------------------------------------------------------------
__global__ __launch_bounds__(256, 2) void attn_agg_kernel(
    const float* __restrict__ target, const float* __restrict__ middle,
    const float* __restrict__ ws, float* __restrict__ out) {
  const int t = threadIdx.x;
  const int w = t >> 6;    // wave in block
  const int l = t & 63;    // lane
  const int n = blockIdx.x * 4 + w;

  const float4* m4p = (const float4*)(middle + (size_t)n * K_ * D_);
  const float4 vv = ((const float4*)ws)[l];                       // v[4l..4l+3]
  const float cadd = ws[D_];
  const float4 tg = ((const float4*)(target + (size_t)n * D_))[l];

  float4 m[K_];
#pragma unroll
  for (int j = 0; j < K_; ++j) m[j] = m4p[j * 64 + l];

  // --- pass 1: dots + value-halving butterfly (peak 16 live partials) ---
  float pd[16];
#pragma unroll
  for (int j = 0; j < 16; ++j) {
    float d = m[j].x * vv.x + m[j].y * vv.y + m[j].z * vv.z + m[j].w * vv.w;
    d += __shfl_xor(d, 32);
    pd[j] = d;
  }
#pragma unroll
  for (int j = 16; j < 32; ++j) {
    float d = m[j].x * vv.x + m[j].y * vv.y + m[j].z * vv.z + m[j].w * vv.w;
    d += __shfl_xor(d, 32);
    pd[j - 16] = (l & 32) ? d : pd[j - 16];   // select by bit5
  }
#pragma unroll
  for (int i = 0; i < 16; ++i) pd[i] += __shfl_xor(pd[i], 16);
#pragma unroll
  for (int i = 0; i < 8; ++i) pd[i] = (l & 16) ? pd[i + 8] : pd[i];
#pragma unroll
  for (int i = 0; i < 8; ++i) pd[i] += __shfl_xor(pd[i], 8);
#pragma unroll
  for (int i = 0; i < 4; ++i) pd[i] = (l & 8) ? pd[i + 4] : pd[i];
#pragma unroll
  for (int i = 0; i < 4; ++i) pd[i] += __shfl_xor(pd[i], 4);
#pragma unroll
  for (int i = 0; i < 2; ++i) pd[i] = (l & 4) ? pd[i + 2] : pd[i];
#pragma unroll
  for (int i = 0; i < 2; ++i) pd[i] += __shfl_xor(pd[i], 2);
  pd[0] = (l & 2) ? pd[1] : pd[0];
  pd[0] += __shfl_xor(pd[0], 1);
  // lane l now holds full dot for row j(l) = 16*b5 + 8*b4 + 4*b3 + 2*b2 + b1

  // --- target[n] . v : full-wave butterfly, every lane gets the total ---
  float tp = tg.x * vv.x + tg.y * vv.y + tg.z * vv.z + tg.w * vv.w;
  tp += __shfl_xor(tp, 32);
  tp += __shfl_xor(tp, 16);
  tp += __shfl_xor(tp, 8);
  tp += __shfl_xor(tp, 4);
  tp += __shfl_xor(tp, 2);
  tp += __shfl_xor(tp, 1);

  // --- softmax over K=32, fully in-wave (each row duplicated in 2 lanes) ---
  float sc = pd[0] + tp + cadd;
  sc = sc > 0.f ? sc : NEG_SLOPE * sc;   // leaky_relu
  float mx = sc;
  mx = fmaxf(mx, __shfl_xor(mx, 32));
  mx = fmaxf(mx, __shfl_xor(mx, 16));
  mx = fmaxf(mx, __shfl_xor(mx, 8));
  mx = fmaxf(mx, __shfl_xor(mx, 4));
  mx = fmaxf(mx, __shfl_xor(mx, 2));
  mx = fmaxf(mx, __shfl_xor(mx, 1));
  const float ex = __expf(sc - mx);
  float sm = ex;
  sm += __shfl_xor(sm, 32);
  sm += __shfl_xor(sm, 16);
  sm += __shfl_xor(sm, 8);
  sm += __shfl_xor(sm, 4);
  sm += __shfl_xor(sm, 2);
  sm += __shfl_xor(sm, 1);              // = 2 * sum_j ex_j
  const float coef = 2.f * ex / sm;     // lane 2j holds coef of row j

  // --- pass 2: out[n, 4l..4l+3] = sum_j coef_j * m[j] ---
  float4 acc = make_float4(0.f, 0.f, 0.f, 0.f);
#pragma unroll
  for (int j = 0; j < K_; ++j) {
    const float cf =
        __int_as_float(__builtin_amdgcn_readlane(__float_as_int(coef), 2 * j));
    acc.x += cf * m[j].x;
    acc.y += cf * m[j].y;
    acc.z += cf * m[j].z;
    acc.w += cf * m[j].w;
  }
  ((float4*)(out + (size_t)n * D_))[l] = acc;
}

extern "C" void kernel_launch(void* const* d_in, const int* in_sizes, int n_in,
                              void* d_out, int out_size, void* d_ws, size_t ws_size,
                              hipStream_t stream) {
  const float* target = (const float*)d_in[0];
  const float* middle = (const float*)d_in[1];
  const float* W      = (const float*)d_in[2];
  const float* b      = (const float*)d_in[3];
  const float* a_w    = (const float*)d_in[4];
  const float* a_b    = (const float*)d_in[5];
  float* out = (float*)d_out;
  float* ws  = (float*)d_ws;  // needs (D_+1) floats

  hipMemsetAsync(ws, 0, (D_ + 1) * sizeof(float), stream);
  prep_kernel<<<32, 256, 0, stream>>>(W, b, a_w, a_b, ws);
  attn_agg_kernel<<<N_ / 4, 256, 0, stream>>>(target, middle, ws, out);
}

// Round 6
// 108.392 us; speedup vs baseline: 1.1720x; 1.1720x over previous
//
#include <hip/hip_runtime.h>

// Problem constants (reference: N=16384, K=32, D=256)
#define N_ 16384
#define K_ 32
#define D_ 256
#define NEG_SLOPE 0.01f

// ---------------------------------------------------------------------------
// Prologue: ONE dispatch, one block, no atomics (no memset needed).
//   ws[0..255] = v = a_w @ W ; ws[256] = 2*dot(b,a_w) + a_b
// ---------------------------------------------------------------------------
__global__ __launch_bounds__(1024) void prep_kernel(
    const float* __restrict__ W, const float* __restrict__ b,
    const float* __restrict__ a_w, const float* __restrict__ a_b,
    float* __restrict__ ws) {
  __shared__ float part[4][D_];
  __shared__ float sp[4];
  const int t = threadIdx.x;
  const int dd = t >> 8;   // 0..3
  const int e = t & 255;
  float acc = 0.f;
#pragma unroll 8
  for (int j = 0; j < 64; ++j) {
    const int d = dd * 64 + j;
    acc += a_w[d] * W[d * D_ + e];   // coalesced over e
  }
  part[dd][e] = acc;

  // scalar bias term: reduce b[t]*a_w[t] over t<256 (waves 0..3)
  if (t < D_) {
    float s = b[t] * a_w[t];
#pragma unroll
    for (int off = 1; off < 64; off <<= 1) s += __shfl_xor(s, off);
    if ((t & 63) == 0) sp[t >> 6] = s;
  }
  __syncthreads();
  if (t < D_) ws[t] = part[0][t] + part[1][t] + part[2][t] + part[3][t];
  if (t == 0) ws[D_] = 2.f * (sp[0] + sp[1] + sp[2] + sp[3]) + a_b[0];
}

// ---------------------------------------------------------------------------
// Main: one 512-thread block per n. Wave kg owns k-rows 4kg..4kg+3; lane l
// owns columns 4l..4l+3 (m[4] = 16 VGPR). Two barriers only:
//   pass1 dots -> sdot (LDS)  | barrier | softmax redundantly in ALL 8 waves
//   (coef via uniform readlane) -> pass2 on registers -> part (LDS)
//   | barrier | float4 column-sum + single 1KB coalesced store.
// ---------------------------------------------------------------------------
__global__ __launch_bounds__(512, 8) void attn_agg_kernel(
    const float* __restrict__ target, const float* __restrict__ middle,
    const float* __restrict__ ws, float* __restrict__ out) {
  __shared__ __align__(16) float part[8][D_];  // 8 KB
  __shared__ float sdot[K_];
  __shared__ float stp[4];

  const int t = threadIdx.x;
  const int kg = t >> 6;   // wave 0..7, owns k = 4kg..4kg+3
  const int l = t & 63;
  const int n = blockIdx.x;

  const float4* m4p = (const float4*)(middle + (size_t)n * K_ * D_);
  float4 m[4];
#pragma unroll
  for (int j = 0; j < 4; ++j) m[j] = m4p[(kg * 4 + j) * 64 + l];

  const float4 vv = ((const float4*)ws)[l];  // v[4l..4l+3]
  const float cadd = ws[D_];

  // pass 1: partial dots + value-halving butterfly (10 shuffles)
  float pd[4];
#pragma unroll
  for (int j = 0; j < 4; ++j)
    pd[j] = m[j].x * vv.x + m[j].y * vv.y + m[j].z * vv.z + m[j].w * vv.w;
#pragma unroll
  for (int j = 0; j < 4; ++j) pd[j] += __shfl_xor(pd[j], 32);
  float q0 = (l & 32) ? pd[2] : pd[0];
  float q1 = (l & 32) ? pd[3] : pd[1];
  q0 += __shfl_xor(q0, 16);
  q1 += __shfl_xor(q1, 16);
  float r = (l & 16) ? q1 : q0;
  r += __shfl_xor(r, 8);
  r += __shfl_xor(r, 4);
  r += __shfl_xor(r, 2);
  r += __shfl_xor(r, 1);
  if ((l & 15) == 0)
    sdot[kg * 4 + ((l >> 5) * 2 + ((l >> 4) & 1))] = r;

  // target[n] . v (waves 0..3)
  if (t < D_) {
    float tp = target[(size_t)n * D_ + t] * ws[t];
#pragma unroll
    for (int off = 1; off < 64; off <<= 1) tp += __shfl_xor(tp, off);
    if (l == 0) stp[kg] = tp;
  }
  __syncthreads();  // sdot, stp ready

  // softmax over K=32, redundantly in every wave (halves duplicate k=l&31)
  const float tdot = stp[0] + stp[1] + stp[2] + stp[3];
  float sc = sdot[l & 31] + tdot + cadd;
  sc = sc > 0.f ? sc : NEG_SLOPE * sc;  // leaky_relu
  float mx = sc;
  mx = fmaxf(mx, __shfl_xor(mx, 1));
  mx = fmaxf(mx, __shfl_xor(mx, 2));
  mx = fmaxf(mx, __shfl_xor(mx, 4));
  mx = fmaxf(mx, __shfl_xor(mx, 8));
  mx = fmaxf(mx, __shfl_xor(mx, 16));
  const float ex = __expf(sc - mx);
  float sm = ex;
  sm += __shfl_xor(sm, 1);
  sm += __shfl_xor(sm, 2);
  sm += __shfl_xor(sm, 4);
  sm += __shfl_xor(sm, 8);
  sm += __shfl_xor(sm, 16);
  const float coef = ex / sm;  // lane l holds coef[k = l&31] (both halves)

  // pass 2: registers only; coef broadcast via uniform readlane
  float4 acc = make_float4(0.f, 0.f, 0.f, 0.f);
#pragma unroll
  for (int j = 0; j < 4; ++j) {
    const float cf = __int_as_float(
        __builtin_amdgcn_readlane(__float_as_int(coef), kg * 4 + j));
    acc.x += cf * m[j].x;
    acc.y += cf * m[j].y;
    acc.z += cf * m[j].z;
    acc.w += cf * m[j].w;
  }
  *(float4*)(&part[kg][4 * l]) = acc;
  __syncthreads();  // part ready

  // final: wave 0 sums 8 wave-partials, float4, single 1KB coalesced store
  if (t < 64) {
    float4 o = make_float4(0.f, 0.f, 0.f, 0.f);
#pragma unroll
    for (int w = 0; w < 8; ++w) {
      const float4 p = *(const float4*)(&part[w][4 * t]);
      o.x += p.x; o.y += p.y; o.z += p.z; o.w += p.w;
    }
    ((float4*)(out + (size_t)n * D_))[t] = o;
  }
}

extern "C" void kernel_launch(void* const* d_in, const int* in_sizes, int n_in,
                              void* d_out, int out_size, void* d_ws, size_t ws_size,
                              hipStream_t stream) {
  const float* target = (const float*)d_in[0];
  const float* middle = (const float*)d_in[1];
  const float* W      = (const float*)d_in[2];
  const float* b      = (const float*)d_in[3];
  const float* a_w    = (const float*)d_in[4];
  const float* a_b    = (const float*)d_in[5];
  float* out = (float*)d_out;
  float* ws  = (float*)d_ws;  // needs (D_+1) floats

  prep_kernel<<<1, 1024, 0, stream>>>(W, b, a_w, a_b, ws);
  attn_agg_kernel<<<N_, 512, 0, stream>>>(target, middle, ws, out);
}